// Round 1
// baseline (1282.009 us; speedup 1.0000x reference)
//
#include <hip/hip_runtime.h>
#include <math.h>

#define N_NODES 50000
#define N_EDGES 800000
#define E_TOT   850000          // edges + self loops
#define NEG_SLOPE 0.2f

// ---------------------------------------------------------------------------
// float atomic max via int/uint monotonic trick (works for mixed signs)
__device__ __forceinline__ void atomicMaxFloat(float* addr, float val) {
    if (val >= 0.0f) {
        atomicMax((int*)addr, __float_as_int(val));
    } else {
        atomicMin((unsigned int*)addr, __float_as_uint(val));
    }
}

// ---------------------------------------------------------------------------
__global__ void init_kernel(float* m, float* denom, float* acc, int n, int ndo) {
    int i = blockIdx.x * blockDim.x + threadIdx.x;
    if (i < n) { m[i] = -3.402823466e38f; denom[i] = 0.0f; }
    if (i < ndo) acc[i] = 0.0f;
}

// h = X @ W   (X: n x di, W: di x do). W staged in LDS; one thread per (node,c).
template<int DO>
__global__ void gemm_kernel(const float* __restrict__ X, const float* __restrict__ W,
                            float* __restrict__ H, int n, int di) {
    __shared__ float sW[64 * 64];
    const int tid = threadIdx.x;
    const int tot = di * DO;
    for (int i = tid; i < tot; i += blockDim.x) sW[i] = W[i];
    __syncthreads();
    const int npb  = 256 / DO;            // nodes per block
    const int c    = tid & (DO - 1);
    const int nl   = tid / DO;
    const int node = blockIdx.x * npb + nl;
    if (node >= n) return;
    const float* xr = X + node * di;
    float acc = 0.0f;
#pragma unroll 8
    for (int k = 0; k < di; k++) acc += xr[k] * sW[k * DO + c];
    H[node * DO + c] = acc;
}

// per-node attention projections: s_src[n] = h[n].a_src, s_dst[n] = h[n].a_dst
template<int DO>
__global__ void proj_kernel(const float* __restrict__ H,
                            const float* __restrict__ a_src, const float* __restrict__ a_dst,
                            float* __restrict__ ssrc, float* __restrict__ sdst, int n) {
    int node = blockIdx.x * blockDim.x + threadIdx.x;
    if (node >= n) return;
    const float* hr = H + node * DO;
    float ss = 0.0f, sd = 0.0f;
#pragma unroll
    for (int c = 0; c < DO; c++) { float hv = hr[c]; ss += hv * a_src[c]; sd += hv * a_dst[c]; }
    ssrc[node] = ss;
    sdst[node] = sd;
}

// edge pass 1: logits + segment max
__global__ void edge_max_kernel(const int* __restrict__ src, const int* __restrict__ dst,
                                const float* __restrict__ ssrc, const float* __restrict__ sdst,
                                float* __restrict__ ebuf, float* __restrict__ m) {
    int e = blockIdx.x * blockDim.x + threadIdx.x;
    if (e >= E_TOT) return;
    int s, d;
    if (e < N_EDGES) { s = src[e]; d = dst[e]; } else { s = e - N_EDGES; d = s; }
    float v = ssrc[s] + sdst[d];
    v = (v > 0.0f) ? v : NEG_SLOPE * v;          // leaky relu
    ebuf[e] = v;
    atomicMaxFloat(&m[d], v);
}

// edge pass 2: exp(e - m[dst]) + segment sum of denominator
__global__ void edge_exp_kernel(const int* __restrict__ dst,
                                float* __restrict__ ebuf,
                                const float* __restrict__ m, float* __restrict__ denom) {
    int e = blockIdx.x * blockDim.x + threadIdx.x;
    if (e >= E_TOT) return;
    int d = (e < N_EDGES) ? dst[e] : (e - N_EDGES);
    float ex = __expf(ebuf[e] - m[d]);
    ebuf[e] = ex;
    atomicAdd(&denom[d], ex);
}

// edge pass 3: scatter alpha * h[src] into acc[dst]; lane = channel (coalesced)
template<int DO>
__global__ void scatter_kernel(const float* __restrict__ H, const float* __restrict__ ex,
                               const float* __restrict__ denom,
                               const int* __restrict__ src, const int* __restrict__ dst,
                               float* __restrict__ acc) {
    long t = (long)blockIdx.x * blockDim.x + threadIdx.x;
    if (t >= (long)E_TOT * DO) return;
    int c = (int)(t & (DO - 1));
    int e = (int)(t / DO);
    int s, d;
    if (e < N_EDGES) { s = src[e]; d = dst[e]; } else { s = e - N_EDGES; d = s; }
    float alpha = ex[e] / (denom[d] + 1e-16f);
    atomicAdd(&acc[d * DO + c], alpha * H[s * DO + c]);
}

// epilogue: + bias, optional relu into feat_out, optional raw write to extra_out
template<int DO>
__global__ void epilogue_kernel(const float* __restrict__ acc, const float* __restrict__ b,
                                float* __restrict__ feat_out, float* __restrict__ extra_out,
                                int do_relu, int n) {
    int i = blockIdx.x * blockDim.x + threadIdx.x;
    if (i >= n * DO) return;
    int c = i & (DO - 1);
    float v = acc[i] + b[c];
    if (extra_out) extra_out[i] = v;
    if (feat_out) feat_out[i] = do_relu ? fmaxf(v, 0.0f) : v;
}

// ---------------------------------------------------------------------------
struct LayerBufs {
    float *H, *ACC, *SS, *SD, *M, *DEN, *EX;
    const int *src, *dst;
};

template<int DO>
static void run_layer(const LayerBufs& wb, const float* in_feat, int di,
                      const float* W, const float* a_src, const float* a_dst, const float* b,
                      int do_relu, float* feat_out, float* extra_out, hipStream_t stream) {
    const int n = N_NODES;
    // init m/denom/acc
    {
        int tot = n * DO;
        init_kernel<<<(tot + 255) / 256, 256, 0, stream>>>(wb.M, wb.DEN, wb.ACC, n, tot);
    }
    // h = in @ W
    {
        int npb = 256 / DO;
        gemm_kernel<DO><<<(n + npb - 1) / npb, 256, 0, stream>>>(in_feat, W, wb.H, n, di);
    }
    // per-node projections
    proj_kernel<DO><<<(n + 255) / 256, 256, 0, stream>>>(wb.H, a_src, a_dst, wb.SS, wb.SD, n);
    // edge passes
    edge_max_kernel<<<(E_TOT + 255) / 256, 256, 0, stream>>>(wb.src, wb.dst, wb.SS, wb.SD, wb.EX, wb.M);
    edge_exp_kernel<<<(E_TOT + 255) / 256, 256, 0, stream>>>(wb.dst, wb.EX, wb.M, wb.DEN);
    {
        long tot = (long)E_TOT * DO;
        scatter_kernel<DO><<<(int)((tot + 255) / 256), 256, 0, stream>>>(wb.H, wb.EX, wb.DEN,
                                                                         wb.src, wb.dst, wb.ACC);
    }
    // epilogue
    epilogue_kernel<DO><<<(n * DO + 255) / 256, 256, 0, stream>>>(wb.ACC, b, feat_out, extra_out,
                                                                  do_relu, n);
}

extern "C" void kernel_launch(void* const* d_in, const int* in_sizes, int n_in,
                              void* d_out, int out_size, void* d_ws, size_t ws_size,
                              hipStream_t stream) {
    const float* x  = (const float*)d_in[0];
    const int*   ei = (const int*)d_in[1];

    const float* w1  = (const float*)d_in[2];
    const float* as1 = (const float*)d_in[3];
    const float* ad1 = (const float*)d_in[4];
    const float* b1  = (const float*)d_in[5];
    const float* w2  = (const float*)d_in[6];
    const float* as2 = (const float*)d_in[7];
    const float* ad2 = (const float*)d_in[8];
    const float* b2  = (const float*)d_in[9];
    const float* w3  = (const float*)d_in[10];
    const float* as3 = (const float*)d_in[11];
    const float* ad3 = (const float*)d_in[12];
    const float* b3  = (const float*)d_in[13];
    const float* w4  = (const float*)d_in[14];
    const float* as4 = (const float*)d_in[15];
    const float* ad4 = (const float*)d_in[16];
    const float* b4  = (const float*)d_in[17];

    float* out_final = (float*)d_out;                 // [N, 64]
    float* out_h     = (float*)d_out + N_NODES * 64;  // [N, 32] (layer2 pre-relu)

    // workspace layout (floats)
    float* ws = (float*)d_ws;
    float* H    = ws;                         // N*64
    float* ACC  = ws + N_NODES * 64;          // N*64
    float* FEAT = ws + 2 * N_NODES * 64;      // N*64
    float* SS   = ws + 3 * N_NODES * 64;      // N
    float* SD   = SS + N_NODES;               // N
    float* M    = SD + N_NODES;               // N
    float* DEN  = M + N_NODES;                // N
    float* EX   = DEN + N_NODES;              // E_TOT

    LayerBufs wb;
    wb.H = H; wb.ACC = ACC; wb.SS = SS; wb.SD = SD; wb.M = M; wb.DEN = DEN; wb.EX = EX;
    wb.src = ei;               // edge_index row 0
    wb.dst = ei + N_EDGES;     // edge_index row 1

    // layer 1: x(64) -> 64, relu -> FEAT
    run_layer<64>(wb, x, 64, w1, as1, ad1, b1, /*relu=*/1, FEAT, nullptr, stream);
    // layer 2: FEAT(64) -> 32; pre-relu -> out_h, relu -> FEAT
    run_layer<32>(wb, FEAT, 64, w2, as2, ad2, b2, /*relu=*/1, FEAT, out_h, stream);
    // layer 3: FEAT(32) -> 64, relu -> FEAT
    run_layer<64>(wb, FEAT, 32, w3, as3, ad3, b3, /*relu=*/1, FEAT, nullptr, stream);
    // layer 4: FEAT(64) -> 64, no relu, write final out
    run_layer<64>(wb, FEAT, 64, w4, as4, ad4, b4, /*relu=*/0, nullptr, out_final, stream);
}

// Round 3
// 692.465 us; speedup vs baseline: 1.8514x; 1.8514x over previous
//
#include <hip/hip_runtime.h>
#include <math.h>

#define N_NODES 50000
#define N_EDGES 800000
#define E_TOT   850000          // edges + self loops
#define NEG_SLOPE 0.2f

// ===========================================================================
// CSR-by-dst construction (once per call; dst indices shared by all 4 layers)
// ===========================================================================
__global__ void csr_init(int* deg, int* cnt) {
    int i = blockIdx.x * blockDim.x + threadIdx.x;
    if (i < N_NODES) { deg[i] = 0; cnt[i] = 0; }
}

__global__ void csr_degree(const int* __restrict__ dst, int* __restrict__ deg) {
    int e = blockIdx.x * blockDim.x + threadIdx.x;
    if (e >= E_TOT) return;
    int d = (e < N_EDGES) ? dst[e] : (e - N_EDGES);
    atomicAdd(&deg[d], 1);
}

#define SCAN_T 256
__global__ void csr_scan(const int* __restrict__ deg, int* __restrict__ offs) {
    __shared__ int ssum[SCAN_T];
    const int CH = (N_NODES + SCAN_T - 1) / SCAN_T;   // 196
    int t = threadIdx.x;
    int beg = t * CH, end = min(beg + CH, N_NODES);
    int s = 0;
    for (int i = beg; i < end; i++) s += deg[i];
    ssum[t] = s;
    __syncthreads();
    for (int off = 1; off < SCAN_T; off <<= 1) {
        int v = (t >= off) ? ssum[t - off] : 0;
        __syncthreads();
        ssum[t] += v;
        __syncthreads();
    }
    int run = (t == 0) ? 0 : ssum[t - 1];             // exclusive prefix
    for (int i = beg; i < end; i++) { offs[i] = run; run += deg[i]; }
    if (t == SCAN_T - 1) offs[N_NODES] = run;
}

__global__ void csr_fill(const int* __restrict__ src, const int* __restrict__ dst,
                         const int* __restrict__ offs, int* __restrict__ cnt,
                         int* __restrict__ csr_src) {
    int e = blockIdx.x * blockDim.x + threadIdx.x;
    if (e >= E_TOT) return;
    int s, d;
    if (e < N_EDGES) { s = src[e]; d = dst[e]; } else { s = e - N_EDGES; d = s; }
    int pos = offs[d] + atomicAdd(&cnt[d], 1);
    csr_src[pos] = s;
}

// ===========================================================================
// h = X @ W fused with per-node attention projections (shuffle reduction)
// ===========================================================================
template<int DI, int DO>
__global__ void gemm_proj(const float* __restrict__ X, const float* __restrict__ W,
                          const float* __restrict__ a_src, const float* __restrict__ a_dst,
                          float* __restrict__ H, float* __restrict__ ssrc,
                          float* __restrict__ sdst) {
    const int NPB = 256 / DO;                // nodes per block
    __shared__ float sW[DI * DO];
    __shared__ float sX[NPB * DI];
    const int tid = threadIdx.x;
    for (int i = tid; i < DI * DO; i += 256) sW[i] = W[i];
    const int base = blockIdx.x * NPB;
    for (int i = tid; i < NPB * DI; i += 256) {
        int node = base + i / DI;
        sX[i] = (node < N_NODES) ? X[node * DI + i % DI] : 0.0f;
    }
    __syncthreads();
    const int c = tid % DO;
    const int g = tid / DO;
    const int node = base + g;
    if (node >= N_NODES) return;
    float acc = 0.0f;
#pragma unroll
    for (int k = 0; k < DI; k++) acc += sX[g * DI + k] * sW[k * DO + c];
    H[node * DO + c] = acc;
    float ps = acc * a_src[c];
    float pd = acc * a_dst[c];
#pragma unroll
    for (int m = DO / 2; m >= 1; m >>= 1) {
        ps += __shfl_xor(ps, m);
        pd += __shfl_xor(pd, m);
    }
    if (c == 0) { ssrc[node] = ps; sdst[node] = pd; }
}

// ===========================================================================
// Fused per-dst-node softmax + aggregation + bias + relu. One DO-lane group
// per node; no atomics, accumulators in registers.
// ===========================================================================
template<int DO>
__global__ void gather(const float* __restrict__ H, const float* __restrict__ ssrc,
                       const float* __restrict__ sdst, const int* __restrict__ offs,
                       const int* __restrict__ csr_src, const float* __restrict__ bias,
                       float* __restrict__ feat_out, float* __restrict__ extra_out,
                       int do_relu) {
    const long t = (long)blockIdx.x * blockDim.x + threadIdx.x;
    const int node = (int)(t / DO);
    const int c = (int)(t % DO);
    if (node >= N_NODES) return;
    const int beg = offs[node], end = offs[node + 1];
    const float sd = sdst[node];

    // pass 1: segment max (lane-parallel over edges, butterfly reduce)
    float mx = -3.402823466e38f;
    for (int i = beg + c; i < end; i += DO) {
        float v = ssrc[csr_src[i]] + sd;
        v = (v > 0.0f) ? v : NEG_SLOPE * v;
        mx = fmaxf(mx, v);
    }
#pragma unroll
    for (int m = DO / 2; m >= 1; m >>= 1) mx = fmaxf(mx, __shfl_xor(mx, m));

    // pass 2: exp + denom + weighted gather of H rows (group walks edges
    // together; lane = channel → coalesced 4B/lane row reads)
    float acc = 0.0f, den = 0.0f;
    for (int i = beg; i < end; i++) {
        int s = csr_src[i];                       // same addr per group
        float v = ssrc[s] + sd;
        v = (v > 0.0f) ? v : NEG_SLOPE * v;
        float ex = __expf(v - mx);
        den += ex;
        acc += ex * H[(long)s * DO + c];
    }
    float out = acc / (den + 1e-16f) + bias[c];
    long idx = (long)node * DO + c;
    if (extra_out) extra_out[idx] = out;
    if (feat_out) feat_out[idx] = do_relu ? fmaxf(out, 0.0f) : out;
}

// ===========================================================================
template<int DI, int DO>
static void run_layer(const float* in_feat, const float* W, const float* a_src,
                      const float* a_dst, const float* b, int do_relu,
                      float* H, float* SS, float* SD,
                      const int* offs, const int* csr_src,
                      float* feat_out, float* extra_out, hipStream_t stream) {
    const int NPB = 256 / DO;
    gemm_proj<DI, DO><<<(N_NODES + NPB - 1) / NPB, 256, 0, stream>>>(
        in_feat, W, a_src, a_dst, H, SS, SD);
    long tot = (long)N_NODES * DO;
    gather<DO><<<(int)((tot + 255) / 256), 256, 0, stream>>>(
        H, SS, SD, offs, csr_src, b, feat_out, extra_out, do_relu);
}

extern "C" void kernel_launch(void* const* d_in, const int* in_sizes, int n_in,
                              void* d_out, int out_size, void* d_ws, size_t ws_size,
                              hipStream_t stream) {
    const float* x  = (const float*)d_in[0];
    const int*   ei = (const int*)d_in[1];

    const float* w1  = (const float*)d_in[2];
    const float* as1 = (const float*)d_in[3];
    const float* ad1 = (const float*)d_in[4];
    const float* b1  = (const float*)d_in[5];
    const float* w2  = (const float*)d_in[6];
    const float* as2 = (const float*)d_in[7];
    const float* ad2 = (const float*)d_in[8];
    const float* b2  = (const float*)d_in[9];
    const float* w3  = (const float*)d_in[10];
    const float* as3 = (const float*)d_in[11];
    const float* ad3 = (const float*)d_in[12];
    const float* b3  = (const float*)d_in[13];
    const float* w4  = (const float*)d_in[14];
    const float* as4 = (const float*)d_in[15];
    const float* ad4 = (const float*)d_in[16];
    const float* b4  = (const float*)d_in[17];

    float* out_final = (float*)d_out;                 // [N, 64]
    float* out_h     = (float*)d_out + N_NODES * 64;  // [N, 32] (layer2 pre-relu)

    // workspace layout
    float* ws   = (float*)d_ws;
    float* H    = ws;                          // N*64
    float* FEAT = H + N_NODES * 64;            // N*64
    float* SS   = FEAT + N_NODES * 64;         // N
    float* SD   = SS + N_NODES;                // N
    int* deg     = (int*)(SD + N_NODES);       // N
    int* cnt     = deg + N_NODES;              // N
    int* offs    = cnt + N_NODES;              // N+1
    int* csr_src = offs + N_NODES + 1;         // E_TOT

    const int* src = ei;                // edge_index row 0
    const int* dst = ei + N_EDGES;      // edge_index row 1

    // --- build CSR by dst (once; shared by all 4 layers) ---
    csr_init<<<(N_NODES + 255) / 256, 256, 0, stream>>>(deg, cnt);
    csr_degree<<<(E_TOT + 255) / 256, 256, 0, stream>>>(dst, deg);
    csr_scan<<<1, SCAN_T, 0, stream>>>(deg, offs);
    csr_fill<<<(E_TOT + 255) / 256, 256, 0, stream>>>(src, dst, offs, cnt, csr_src);

    // --- 4 GAT layers ---
    // layer 1: x(64) -> 64, relu -> FEAT
    run_layer<64, 64>(x, w1, as1, ad1, b1, 1, H, SS, SD, offs, csr_src, FEAT, nullptr, stream);
    // layer 2: FEAT(64) -> 32; pre-relu -> out_h, relu -> FEAT
    run_layer<64, 32>(FEAT, w2, as2, ad2, b2, 1, H, SS, SD, offs, csr_src, FEAT, out_h, stream);
    // layer 3: FEAT(32) -> 64, relu -> FEAT
    run_layer<32, 64>(FEAT, w3, as3, ad3, b3, 1, H, SS, SD, offs, csr_src, FEAT, nullptr, stream);
    // layer 4: FEAT(64) -> 64, no relu -> final out
    run_layer<64, 64>(FEAT, w4, as4, ad4, b4, 0, H, SS, SD, offs, csr_src, nullptr, out_final, stream);
}

// Round 4
// 439.872 us; speedup vs baseline: 2.9145x; 1.5742x over previous
//
#include <hip/hip_runtime.h>
#include <math.h>

#define N_NODES 50000
#define N_EDGES 800000
#define E_TOT   850000          // edges + self loops
#define NEG_SLOPE 0.2f

// ===========================================================================
// CSR-by-dst construction (once per call; dst indices shared by all 4 layers)
// ===========================================================================
__global__ void csr_init(int* deg, int* cnt) {
    int i = blockIdx.x * blockDim.x + threadIdx.x;
    if (i < N_NODES) { deg[i] = 0; cnt[i] = 0; }
}

__global__ void csr_degree(const int* __restrict__ dst, int* __restrict__ deg) {
    int e = blockIdx.x * blockDim.x + threadIdx.x;
    if (e >= E_TOT) return;
    int d = (e < N_EDGES) ? dst[e] : (e - N_EDGES);
    atomicAdd(&deg[d], 1);
}

#define SCAN_T 1024
__global__ void csr_scan(const int* __restrict__ deg, int* __restrict__ offs) {
    __shared__ int ssum[SCAN_T];
    const int CH = (N_NODES + SCAN_T - 1) / SCAN_T;   // 49
    int t = threadIdx.x;
    int beg = t * CH, end = min(beg + CH, N_NODES);
    int s = 0;
    for (int i = beg; i < end; i++) s += deg[i];
    ssum[t] = s;
    __syncthreads();
    for (int off = 1; off < SCAN_T; off <<= 1) {
        int v = (t >= off) ? ssum[t - off] : 0;
        __syncthreads();
        ssum[t] += v;
        __syncthreads();
    }
    int run = (t == 0) ? 0 : ssum[t - 1];             // exclusive prefix
    for (int i = beg; i < end; i++) { offs[i] = run; run += deg[i]; }
    if (t == SCAN_T - 1) offs[N_NODES] = run;
}

__global__ void csr_fill(const int* __restrict__ src, const int* __restrict__ dst,
                         const int* __restrict__ offs, int* __restrict__ cnt,
                         int* __restrict__ csr_src) {
    int e = blockIdx.x * blockDim.x + threadIdx.x;
    if (e >= E_TOT) return;
    int s, d;
    if (e < N_EDGES) { s = src[e]; d = dst[e]; } else { s = e - N_EDGES; d = s; }
    int pos = offs[d] + atomicAdd(&cnt[d], 1);
    csr_src[pos] = s;
}

// ===========================================================================
// h = X @ W fused with attention projections. 4 channels/thread via float4
// on sW (contiguous in c) -> 16 FMA per (ds_read_b128 + broadcast b32).
// ===========================================================================
template<int DI, int DO>
__global__ void gemm_proj(const float* __restrict__ X, const float* __restrict__ W,
                          const float* __restrict__ a_src, const float* __restrict__ a_dst,
                          float* __restrict__ H, float* __restrict__ ssrc,
                          float* __restrict__ sdst) {
    const int TPN = DO / 4;          // threads per node
    const int NPB = 256 / TPN;       // nodes per block
    __shared__ float sW[DI * DO];
    __shared__ float sX[NPB][DI + 1];          // +1: break broadcast bank aliasing
    const int tid = threadIdx.x;
    for (int i = tid; i < DI * DO / 4; i += 256)
        ((float4*)sW)[i] = ((const float4*)W)[i];
    const int base = blockIdx.x * NPB;
    for (int i = tid; i < NPB * DI; i += 256) {
        int r = i / DI, col = i % DI;
        int node = base + r;
        sX[r][col] = (node < N_NODES) ? X[(long)node * DI + col] : 0.0f;
    }
    __syncthreads();
    const int cq = tid % TPN;
    const int g  = tid / TPN;
    const int node = base + g;
    if (node >= N_NODES) return;
    float ax = 0.0f, ay = 0.0f, az = 0.0f, aw = 0.0f;
    const float4* sW4 = (const float4*)sW;
#pragma unroll
    for (int k = 0; k < DI; k++) {
        float xv = sX[g][k];
        float4 w4 = sW4[k * TPN + cq];
        ax = fmaf(xv, w4.x, ax); ay = fmaf(xv, w4.y, ay);
        az = fmaf(xv, w4.z, az); aw = fmaf(xv, w4.w, aw);
    }
    float4 hv; hv.x = ax; hv.y = ay; hv.z = az; hv.w = aw;
    ((float4*)H)[(long)node * TPN + cq] = hv;
    float4 as4 = ((const float4*)a_src)[cq];
    float4 ad4 = ((const float4*)a_dst)[cq];
    float ps = ax * as4.x + ay * as4.y + az * as4.z + aw * as4.w;
    float pd = ax * ad4.x + ay * ad4.y + az * ad4.z + aw * ad4.w;
#pragma unroll
    for (int m = TPN / 2; m >= 1; m >>= 1) {
        ps += __shfl_xor(ps, m, TPN);
        pd += __shfl_xor(pd, m, TPN);
    }
    if (cq == 0) { ssrc[node] = ps; sdst[node] = pd; }
}

// ===========================================================================
// Fused softmax + aggregation. Edge slice loaded lane-parallel ONCE (s, logit,
// exp, denom all lane-parallel); sequential loop only broadcasts via __shfl
// and loads the coalesced H row — unrolled x4 so 4 loads are in flight.
// ===========================================================================
template<int DO>
__global__ void gather(const float* __restrict__ H, const float* __restrict__ ssrc,
                       const float* __restrict__ sdst, const int* __restrict__ offs,
                       const int* __restrict__ csr_src, const float* __restrict__ bias,
                       float* __restrict__ feat_out, float* __restrict__ extra_out,
                       int do_relu) {
    const int lane = threadIdx.x % DO;               // channel AND edge-slot idx
    const int node = blockIdx.x * (256 / DO) + threadIdx.x / DO;
    if (node >= N_NODES) return;
    const int beg = offs[node], end = offs[node + 1];
    const int deg = end - beg;
    const float sdv = sdst[node];

    // chunk 0 (covers all edges when deg <= DO — the common case)
    int   s0 = 0;
    float v0 = -3.402823466e38f;
    if (lane < deg) {
        s0 = csr_src[beg + lane];
        float v = ssrc[s0] + sdv;
        v0 = (v > 0.0f) ? v : NEG_SLOPE * v;
    }
    float mx = v0;
    for (int i = beg + DO + lane; i < end; i += DO) {            // rare overflow
        int s = csr_src[i];
        float v = ssrc[s] + sdv;
        v = (v > 0.0f) ? v : NEG_SLOPE * v;
        mx = fmaxf(mx, v);
    }
#pragma unroll
    for (int m = DO / 2; m >= 1; m >>= 1) mx = fmaxf(mx, __shfl_xor(mx, m, DO));

    float acc = 0.0f, den = 0.0f;
    {   // chunk 0 accumulate (reuses registers, no reload)
        int cnt = min(DO, deg);
        float ex = (lane < cnt) ? __expf(v0 - mx) : 0.0f;
        den = ex;
        int j = 0;
        for (; j + 4 <= cnt; j += 4) {
            int   sa = __shfl(s0, j,     DO), sb = __shfl(s0, j + 1, DO);
            int   sc = __shfl(s0, j + 2, DO), sx = __shfl(s0, j + 3, DO);
            float ea = __shfl(ex, j,     DO), eb = __shfl(ex, j + 1, DO);
            float ec = __shfl(ex, j + 2, DO), ed = __shfl(ex, j + 3, DO);
            float ha = H[(long)sa * DO + lane];
            float hb = H[(long)sb * DO + lane];
            float hc = H[(long)sc * DO + lane];
            float hd = H[(long)sx * DO + lane];
            acc = fmaf(ea, ha, acc); acc = fmaf(eb, hb, acc);
            acc = fmaf(ec, hc, acc); acc = fmaf(ed, hd, acc);
        }
        for (; j < cnt; j++) {
            int   sa = __shfl(s0, j, DO);
            float ea = __shfl(ex, j, DO);
            acc = fmaf(ea, H[(long)sa * DO + lane], acc);
        }
    }
    for (int cb = beg + DO; cb < end; cb += DO) {                // rare overflow
        int cnt = min(DO, end - cb);
        int s = 0; float ex = 0.0f;
        if (lane < cnt) {
            s = csr_src[cb + lane];
            float v = ssrc[s] + sdv;
            v = (v > 0.0f) ? v : NEG_SLOPE * v;
            ex = __expf(v - mx);
        }
        den += ex;
        for (int j = 0; j < cnt; j++) {
            int   sa = __shfl(s, j, DO);
            float ea = __shfl(ex, j, DO);
            acc = fmaf(ea, H[(long)sa * DO + lane], acc);
        }
    }
#pragma unroll
    for (int m = DO / 2; m >= 1; m >>= 1) den += __shfl_xor(den, m, DO);

    float out = acc / (den + 1e-16f) + bias[lane];
    long idx = (long)node * DO + lane;
    if (extra_out) extra_out[idx] = out;
    if (feat_out)  feat_out[idx]  = do_relu ? fmaxf(out, 0.0f) : out;
}

// ===========================================================================
template<int DI, int DO>
static void run_layer(const float* in_feat, const float* W, const float* a_src,
                      const float* a_dst, const float* b, int do_relu,
                      float* H, float* SS, float* SD,
                      const int* offs, const int* csr_src,
                      float* feat_out, float* extra_out, hipStream_t stream) {
    const int TPN = DO / 4;
    const int NPB = 256 / TPN;
    gemm_proj<DI, DO><<<(N_NODES + NPB - 1) / NPB, 256, 0, stream>>>(
        in_feat, W, a_src, a_dst, H, SS, SD);
    long tot = (long)N_NODES * DO;
    gather<DO><<<(int)((tot + 255) / 256), 256, 0, stream>>>(
        H, SS, SD, offs, csr_src, b, feat_out, extra_out, do_relu);
}

extern "C" void kernel_launch(void* const* d_in, const int* in_sizes, int n_in,
                              void* d_out, int out_size, void* d_ws, size_t ws_size,
                              hipStream_t stream) {
    const float* x  = (const float*)d_in[0];
    const int*   ei = (const int*)d_in[1];

    const float* w1  = (const float*)d_in[2];
    const float* as1 = (const float*)d_in[3];
    const float* ad1 = (const float*)d_in[4];
    const float* b1  = (const float*)d_in[5];
    const float* w2  = (const float*)d_in[6];
    const float* as2 = (const float*)d_in[7];
    const float* ad2 = (const float*)d_in[8];
    const float* b2  = (const float*)d_in[9];
    const float* w3  = (const float*)d_in[10];
    const float* as3 = (const float*)d_in[11];
    const float* ad3 = (const float*)d_in[12];
    const float* b3  = (const float*)d_in[13];
    const float* w4  = (const float*)d_in[14];
    const float* as4 = (const float*)d_in[15];
    const float* ad4 = (const float*)d_in[16];
    const float* b4  = (const float*)d_in[17];

    float* out_final = (float*)d_out;                 // [N, 64]
    float* out_h     = (float*)d_out + N_NODES * 64;  // [N, 32] (layer2 pre-relu)

    // workspace layout
    float* ws   = (float*)d_ws;
    float* H    = ws;                          // N*64
    float* FEAT = H + N_NODES * 64;            // N*64
    float* SS   = FEAT + N_NODES * 64;         // N
    float* SD   = SS + N_NODES;                // N
    int* deg     = (int*)(SD + N_NODES);       // N
    int* cnt     = deg + N_NODES;              // N
    int* offs    = cnt + N_NODES;              // N+1
    int* csr_src = offs + N_NODES + 1;         // E_TOT

    const int* src = ei;                // edge_index row 0
    const int* dst = ei + N_EDGES;      // edge_index row 1

    // --- build CSR by dst (once; shared by all 4 layers) ---
    csr_init<<<(N_NODES + 255) / 256, 256, 0, stream>>>(deg, cnt);
    csr_degree<<<(E_TOT + 255) / 256, 256, 0, stream>>>(dst, deg);
    csr_scan<<<1, SCAN_T, 0, stream>>>(deg, offs);
    csr_fill<<<(E_TOT + 255) / 256, 256, 0, stream>>>(src, dst, offs, cnt, csr_src);

    // --- 4 GAT layers ---
    run_layer<64, 64>(x, w1, as1, ad1, b1, 1, H, SS, SD, offs, csr_src, FEAT, nullptr, stream);
    run_layer<64, 32>(FEAT, w2, as2, ad2, b2, 1, H, SS, SD, offs, csr_src, FEAT, out_h, stream);
    run_layer<32, 64>(FEAT, w3, as3, ad3, b3, 1, H, SS, SD, offs, csr_src, FEAT, nullptr, stream);
    run_layer<64, 64>(FEAT, w4, as4, ad4, b4, 0, H, SS, SD, offs, csr_src, nullptr, out_final, stream);
}

// Round 5
// 372.523 us; speedup vs baseline: 3.4414x; 1.1808x over previous
//
#include <hip/hip_runtime.h>
#include <math.h>

#define N_NODES 50000
#define N_EDGES 800000
#define E_TOT   850000          // edges + self loops
#define NEG_SLOPE 0.2f
#define NB_SCAN 49              // ceil(N_NODES / 1024)

// ===========================================================================
// CSR-by-dst construction (once per call; dst indices shared by all 4 layers)
// ===========================================================================
__global__ void csr_init(int* deg, int* cnt) {
    int i = blockIdx.x * blockDim.x + threadIdx.x;
    if (i < N_NODES) { deg[i] = 0; cnt[i] = 0; }
}

__global__ void csr_degree(const int* __restrict__ dst, int* __restrict__ deg) {
    int e = blockIdx.x * blockDim.x + threadIdx.x;
    if (e >= E_TOT) return;
    int d = (e < N_EDGES) ? dst[e] : (e - N_EDGES);
    atomicAdd(&deg[d], 1);
}

// --- hierarchical exclusive scan of deg[0..N) -> offs[0..N] ---------------
__global__ void scan_p1(const int* __restrict__ deg, int* __restrict__ bsum) {
    __shared__ int red[1024];
    int i = blockIdx.x * 1024 + threadIdx.x;
    red[threadIdx.x] = (i < N_NODES) ? deg[i] : 0;
    __syncthreads();
    for (int off = 512; off >= 1; off >>= 1) {
        if (threadIdx.x < off) red[threadIdx.x] += red[threadIdx.x + off];
        __syncthreads();
    }
    if (threadIdx.x == 0) bsum[blockIdx.x] = red[0];
}

__global__ void scan_p2(const int* __restrict__ bsum, int* __restrict__ boff,
                        int* __restrict__ offs) {
    int t = threadIdx.x;                       // one wave of 64
    int d = (t < NB_SCAN) ? bsum[t] : 0;
    int v = d;
    for (int off = 1; off < 64; off <<= 1) {
        int u = __shfl_up(v, off, 64);
        if (t >= off) v += u;
    }
    if (t < NB_SCAN) boff[t] = v - d;          // exclusive
    if (t == 63) offs[N_NODES] = v;            // grand total
}

__global__ void scan_p3(const int* __restrict__ deg, const int* __restrict__ boff,
                        int* __restrict__ offs) {
    __shared__ int s[1024];
    int i = blockIdx.x * 1024 + threadIdx.x;
    int v = (i < N_NODES) ? deg[i] : 0;
    s[threadIdx.x] = v;
    __syncthreads();
    for (int off = 1; off < 1024; off <<= 1) {
        int u = (threadIdx.x >= off) ? s[threadIdx.x - off] : 0;
        __syncthreads();
        s[threadIdx.x] += u;
        __syncthreads();
    }
    if (i < N_NODES) offs[i] = boff[blockIdx.x] + s[threadIdx.x] - v;   // exclusive
}

__global__ void csr_fill(const int* __restrict__ src, const int* __restrict__ dst,
                         const int* __restrict__ offs, int* __restrict__ cnt,
                         int* __restrict__ csr_src) {
    int e = blockIdx.x * blockDim.x + threadIdx.x;
    if (e >= E_TOT) return;
    int s, d;
    if (e < N_EDGES) { s = src[e]; d = dst[e]; } else { s = e - N_EDGES; d = s; }
    int pos = offs[d] + atomicAdd(&cnt[d], 1);
    csr_src[pos] = s;
}

// ===========================================================================
// h = X @ W fused with attention projections. 4 channels/thread via float4
// on sW (contiguous in c) -> 16 FMA per (ds_read_b128 + broadcast b32).
// ===========================================================================
template<int DI, int DO>
__global__ void gemm_proj(const float* __restrict__ X, const float* __restrict__ W,
                          const float* __restrict__ a_src, const float* __restrict__ a_dst,
                          float* __restrict__ H, float* __restrict__ ssrc,
                          float* __restrict__ sdst) {
    const int TPN = DO / 4;          // threads per node
    const int NPB = 256 / TPN;       // nodes per block
    __shared__ float sW[DI * DO];
    __shared__ float sX[NPB][DI + 1];          // +1: break broadcast bank aliasing
    const int tid = threadIdx.x;
    for (int i = tid; i < DI * DO / 4; i += 256)
        ((float4*)sW)[i] = ((const float4*)W)[i];
    const int base = blockIdx.x * NPB;
    for (int i = tid; i < NPB * DI; i += 256) {
        int r = i / DI, col = i % DI;
        int node = base + r;
        sX[r][col] = (node < N_NODES) ? X[(long)node * DI + col] : 0.0f;
    }
    __syncthreads();
    const int cq = tid % TPN;
    const int g  = tid / TPN;
    const int node = base + g;
    if (node >= N_NODES) return;
    float ax = 0.0f, ay = 0.0f, az = 0.0f, aw = 0.0f;
    const float4* sW4 = (const float4*)sW;
#pragma unroll
    for (int k = 0; k < DI; k++) {
        float xv = sX[g][k];
        float4 w4 = sW4[k * TPN + cq];
        ax = fmaf(xv, w4.x, ax); ay = fmaf(xv, w4.y, ay);
        az = fmaf(xv, w4.z, az); aw = fmaf(xv, w4.w, aw);
    }
    float4 hv; hv.x = ax; hv.y = ay; hv.z = az; hv.w = aw;
    ((float4*)H)[(long)node * TPN + cq] = hv;
    float4 as4 = ((const float4*)a_src)[cq];
    float4 ad4 = ((const float4*)a_dst)[cq];
    float ps = ax * as4.x + ay * as4.y + az * as4.z + aw * as4.w;
    float pd = ax * ad4.x + ay * ad4.y + az * ad4.z + aw * ad4.w;
#pragma unroll
    for (int m = TPN / 2; m >= 1; m >>= 1) {
        ps += __shfl_xor(ps, m, TPN);
        pd += __shfl_xor(pd, m, TPN);
    }
    if (cq == 0) { ssrc[node] = ps; sdst[node] = pd; }
}

// ===========================================================================
// Fused softmax + aggregation. Edge slice loaded lane-parallel ONCE; the
// sequential loop only __shfl-broadcasts and loads the coalesced H row,
// unrolled x4 so 4 loads are in flight.
// ===========================================================================
template<int DO>
__global__ void gather(const float* __restrict__ H, const float* __restrict__ ssrc,
                       const float* __restrict__ sdst, const int* __restrict__ offs,
                       const int* __restrict__ csr_src, const float* __restrict__ bias,
                       float* __restrict__ feat_out, float* __restrict__ extra_out,
                       int do_relu) {
    const int lane = threadIdx.x % DO;               // channel AND edge-slot idx
    const int node = blockIdx.x * (256 / DO) + threadIdx.x / DO;
    if (node >= N_NODES) return;
    const int beg = offs[node], end = offs[node + 1];
    const int deg = end - beg;
    const float sdv = sdst[node];

    // chunk 0 (covers all edges when deg <= DO — the common case)
    int   s0 = 0;
    float v0 = -3.402823466e38f;
    if (lane < deg) {
        s0 = csr_src[beg + lane];
        float v = ssrc[s0] + sdv;
        v0 = (v > 0.0f) ? v : NEG_SLOPE * v;
    }
    float mx = v0;
    for (int i = beg + DO + lane; i < end; i += DO) {            // rare overflow
        int s = csr_src[i];
        float v = ssrc[s] + sdv;
        v = (v > 0.0f) ? v : NEG_SLOPE * v;
        mx = fmaxf(mx, v);
    }
#pragma unroll
    for (int m = DO / 2; m >= 1; m >>= 1) mx = fmaxf(mx, __shfl_xor(mx, m, DO));

    float acc = 0.0f, den = 0.0f;
    {   // chunk 0 accumulate (reuses registers, no reload)
        int cnt = min(DO, deg);
        float ex = (lane < cnt) ? __expf(v0 - mx) : 0.0f;
        den = ex;
        int j = 0;
        for (; j + 4 <= cnt; j += 4) {
            int   sa = __shfl(s0, j,     DO), sb = __shfl(s0, j + 1, DO);
            int   sc = __shfl(s0, j + 2, DO), sx = __shfl(s0, j + 3, DO);
            float ea = __shfl(ex, j,     DO), eb = __shfl(ex, j + 1, DO);
            float ec = __shfl(ex, j + 2, DO), ed = __shfl(ex, j + 3, DO);
            float ha = H[(long)sa * DO + lane];
            float hb = H[(long)sb * DO + lane];
            float hc = H[(long)sc * DO + lane];
            float hd = H[(long)sx * DO + lane];
            acc = fmaf(ea, ha, acc); acc = fmaf(eb, hb, acc);
            acc = fmaf(ec, hc, acc); acc = fmaf(ed, hd, acc);
        }
        for (; j < cnt; j++) {
            int   sa = __shfl(s0, j, DO);
            float ea = __shfl(ex, j, DO);
            acc = fmaf(ea, H[(long)sa * DO + lane], acc);
        }
    }
    for (int cb = beg + DO; cb < end; cb += DO) {                // rare overflow
        int cnt = min(DO, end - cb);
        int s = 0; float ex = 0.0f;
        if (lane < cnt) {
            s = csr_src[cb + lane];
            float v = ssrc[s] + sdv;
            v = (v > 0.0f) ? v : NEG_SLOPE * v;
            ex = __expf(v - mx);
        }
        den += ex;
        for (int j = 0; j < cnt; j++) {
            int   sa = __shfl(s, j, DO);
            float ea = __shfl(ex, j, DO);
            acc = fmaf(ea, H[(long)sa * DO + lane], acc);
        }
    }
#pragma unroll
    for (int m = DO / 2; m >= 1; m >>= 1) den += __shfl_xor(den, m, DO);

    float out = acc / (den + 1e-16f) + bias[lane];
    long idx = (long)node * DO + lane;
    if (extra_out) extra_out[idx] = out;
    if (feat_out)  feat_out[idx]  = do_relu ? fmaxf(out, 0.0f) : out;
}

// ===========================================================================
template<int DI, int DO>
static void run_layer(const float* in_feat, const float* W, const float* a_src,
                      const float* a_dst, const float* b, int do_relu,
                      float* H, float* SS, float* SD,
                      const int* offs, const int* csr_src,
                      float* feat_out, float* extra_out, hipStream_t stream) {
    const int TPN = DO / 4;
    const int NPB = 256 / TPN;
    gemm_proj<DI, DO><<<(N_NODES + NPB - 1) / NPB, 256, 0, stream>>>(
        in_feat, W, a_src, a_dst, H, SS, SD);
    long tot = (long)N_NODES * DO;
    gather<DO><<<(int)((tot + 255) / 256), 256, 0, stream>>>(
        H, SS, SD, offs, csr_src, b, feat_out, extra_out, do_relu);
}

extern "C" void kernel_launch(void* const* d_in, const int* in_sizes, int n_in,
                              void* d_out, int out_size, void* d_ws, size_t ws_size,
                              hipStream_t stream) {
    const float* x  = (const float*)d_in[0];
    const int*   ei = (const int*)d_in[1];

    const float* w1  = (const float*)d_in[2];
    const float* as1 = (const float*)d_in[3];
    const float* ad1 = (const float*)d_in[4];
    const float* b1  = (const float*)d_in[5];
    const float* w2  = (const float*)d_in[6];
    const float* as2 = (const float*)d_in[7];
    const float* ad2 = (const float*)d_in[8];
    const float* b2  = (const float*)d_in[9];
    const float* w3  = (const float*)d_in[10];
    const float* as3 = (const float*)d_in[11];
    const float* ad3 = (const float*)d_in[12];
    const float* b3  = (const float*)d_in[13];
    const float* w4  = (const float*)d_in[14];
    const float* as4 = (const float*)d_in[15];
    const float* ad4 = (const float*)d_in[16];
    const float* b4  = (const float*)d_in[17];

    float* out_final = (float*)d_out;                 // [N, 64]
    float* out_h     = (float*)d_out + N_NODES * 64;  // [N, 32] (layer2 pre-relu)

    // workspace layout
    float* ws   = (float*)d_ws;
    float* H    = ws;                          // N*64
    float* FEAT = H + N_NODES * 64;            // N*64
    float* SS   = FEAT + N_NODES * 64;         // N
    float* SD   = SS + N_NODES;                // N
    int* deg     = (int*)(SD + N_NODES);       // N
    int* cnt     = deg + N_NODES;              // N
    int* offs    = cnt + N_NODES;              // N+1
    int* csr_src = offs + N_NODES + 1;         // E_TOT
    int* bsum    = csr_src + E_TOT;            // NB_SCAN
    int* boff    = bsum + NB_SCAN;             // NB_SCAN

    const int* src = ei;                // edge_index row 0
    const int* dst = ei + N_EDGES;      // edge_index row 1

    // --- build CSR by dst (once; shared by all 4 layers) ---
    csr_init<<<(N_NODES + 255) / 256, 256, 0, stream>>>(deg, cnt);
    csr_degree<<<(E_TOT + 255) / 256, 256, 0, stream>>>(dst, deg);
    scan_p1<<<NB_SCAN, 1024, 0, stream>>>(deg, bsum);
    scan_p2<<<1, 64, 0, stream>>>(bsum, boff, offs);
    scan_p3<<<NB_SCAN, 1024, 0, stream>>>(deg, boff, offs);
    csr_fill<<<(E_TOT + 255) / 256, 256, 0, stream>>>(src, dst, offs, cnt, csr_src);

    // --- 4 GAT layers ---
    run_layer<64, 64>(x, w1, as1, ad1, b1, 1, H, SS, SD, offs, csr_src, FEAT, nullptr, stream);
    run_layer<64, 32>(FEAT, w2, as2, ad2, b2, 1, H, SS, SD, offs, csr_src, FEAT, out_h, stream);
    run_layer<32, 64>(FEAT, w3, as3, ad3, b3, 1, H, SS, SD, offs, csr_src, FEAT, nullptr, stream);
    run_layer<64, 64>(FEAT, w4, as4, ad4, b4, 0, H, SS, SD, offs, csr_src, nullptr, out_final, stream);
}